// Round 15
// baseline (204.817 us; speedup 1.0000x reference)
//
#include <hip/hip_runtime.h>

#define BSZ   64
#define TLEN  2048
#define NSTEP 2047
#define CIN   8
#define NCH   128     // G slots per batch (16 steps each)
#define CHL   8       // steps per sub-chain; wave does two adjacent sub-chains

typedef __attribute__((ext_vector_type(4))) float    fx4;
typedef __attribute__((ext_vector_type(4))) _Float16 hx4;

// pack 4 f32 -> 4 f16 (rtz)
__device__ __forceinline__ hx4 pk4(float a, float b, float c, float d) {
    auto p0 = __builtin_amdgcn_cvt_pkrtz(a, b);
    auto p1 = __builtin_amdgcn_cvt_pkrtz(c, d);
    hx4 r; r[0] = p0[0]; r[1] = p0[1]; r[2] = p1[0]; r[3] = p1[1];
    return r;
}

// f32 -> f16 hi(rne)/lo(rtz) split: hi+lo ~2^-21 relative
__device__ __forceinline__ void splitf(const fx4 v, hx4& hi, hx4& lo) {
    _Float16 h0 = (_Float16)v[0], h1 = (_Float16)v[1];
    _Float16 h2 = (_Float16)v[2], h3 = (_Float16)v[3];
    hi[0] = h0; hi[1] = h1; hi[2] = h2; hi[3] = h3;
    lo = pk4(v[0] - (float)h0, v[1] - (float)h1, v[2] - (float)h2, v[3] - (float)h3);
}

// D = A*B, 3-term split (hh + h*l + l*h)
__device__ __forceinline__ fx4 mm3(hx4 ah, hx4 al, hx4 bh, hx4 bl) {
    fx4 acc = {0.f, 0.f, 0.f, 0.f};
    acc = __builtin_amdgcn_mfma_f32_16x16x16f16(ah, bh, acc, 0, 0, 0);
    acc = __builtin_amdgcn_mfma_f32_16x16x16f16(ah, bl, acc, 0, 0, 0);
    acc = __builtin_amdgcn_mfma_f32_16x16x16f16(al, bh, acc, 0, 0, 0);
    return acc;
}

// exact MFMA transpose of f16 halves
__device__ __forceinline__ void mfmaT(hx4 Mh, hx4 Ml, hx4 Ih, hx4& Th, hx4& Tl) {
    fx4 z = {0.f, 0.f, 0.f, 0.f};
    fx4 th = __builtin_amdgcn_mfma_f32_16x16x16f16(Mh, Ih, z, 0, 0, 0);
    fx4 tl = __builtin_amdgcn_mfma_f32_16x16x16f16(Ml, Ih, z, 0, 0, 0);
    Th = pk4(th[0], th[1], th[2], th[3]);
    Tl = pk4(tl[0], tl[1], tl[2], tl[3]);
}

// Acc <- Q @ Acc
__device__ __forceinline__ fx4 foldQ(fx4 Q, fx4 Acc, hx4 Ih) {
    hx4 Qh, Ql, Th, Tl, Bh, Bl;
    splitf(Q, Qh, Ql);
    mfmaT(Qh, Ql, Ih, Th, Tl);
    splitf(Acc, Bh, Bl);
    return mm3(Th, Tl, Bh, Bl);
}

// inf-norm of skew S via MFMA: rowsum(|S|) broadcast; fmax + 2 shfl
__device__ __forceinline__ float infnormS(fx4 s, hx4 Oh) {
    hx4 sab = pk4(fabsf(s[0]), fabsf(s[1]), fabsf(s[2]), fabsf(s[3]));
    fx4 z = {0.f, 0.f, 0.f, 0.f};
    fx4 rs = __builtin_amdgcn_mfma_f32_16x16x16f16(sab, Oh, z, 0, 0, 0);
    float a = fmaxf(fmaxf(rs[0], rs[1]), fmaxf(rs[2], rs[3]));
    a = fmaxf(a, __shfl_xor(a, 16, 64));
    a = fmaxf(a, __shfl_xor(a, 32, 64));
    return a;
}

__device__ __forceinline__ void loadDx(const float* __restrict__ X, int b, int t,
                                       float dx[CIN]) {
    if (t < NSTEP) {
        const float* xp = X + ((size_t)b * TLEN + t) * CIN;
        const float4 x0 = *reinterpret_cast<const float4*>(xp + 0);
        const float4 x1 = *reinterpret_cast<const float4*>(xp + 4);
        const float4 y0 = *reinterpret_cast<const float4*>(xp + 8);
        const float4 y1 = *reinterpret_cast<const float4*>(xp + 12);
        dx[0] = y0.x - x0.x; dx[1] = y0.y - x0.y; dx[2] = y0.z - x0.z; dx[3] = y0.w - x0.w;
        dx[4] = y1.x - x1.x; dx[5] = y1.y - x1.y; dx[6] = y1.z - x1.z; dx[7] = y1.w - x1.w;
    } else {
#pragma unroll
        for (int i = 0; i < CIN; ++i) dx[i] = 0.f;   // S=0 -> R=I
    }
}

// 8192 waves total (2048 blocks x 4 waves): wave j of batch b advances the two
// ADJACENT 8-step sub-chains [16j,16j+8) and [16j+8,16j+16) as ILP-2, merges
// P1@P0, stores one 16-step product to G slot j. Same G layout/reduce as r13.
__global__ __launch_bounds__(256, 8)
void devnet_expm_chunk(const float* __restrict__ X, const float* __restrict__ A,
                       float* __restrict__ G)
{
    const int tid  = threadIdx.x;
    const int wid  = tid >> 6;
    const int lane = tid & 63;
    const int m    = lane >> 4;
    const int c    = lane & 15;
    const int gw   = blockIdx.x * 4 + wid;   // 0..8191
    const int b    = gw >> 7;                // 128 waves per batch
    const int j    = gw & 127;               // G slot

    // A_skew fragment: rows 4m+r, col c, 8 channels
    float ask[4][CIN];
#pragma unroll
    for (int r = 0; r < 4; ++r) {
        const int i = 4 * m + r;
#pragma unroll
        for (int cc = 0; cc < CIN; ++cc)
            ask[r][cc] = A[(i * 16 + c) * CIN + cc] - A[(c * 16 + i) * CIN + cc];
    }

    fx4 idv;
#pragma unroll
    for (int r = 0; r < 4; ++r) idv[r] = (4 * m + r == c) ? 1.f : 0.f;
    const hx4 Ih = pk4(idv[0], idv[1], idv[2], idv[3]);
    const hx4 Oh = pk4(1.f, 1.f, 1.f, 1.f);

    fx4 P0 = idv, P1 = idv;
    const int base = 16 * j;

    for (int tt = 0; tt < CHL; ++tt) {
        const int ta = base + tt;          // <= 2039: always valid
        const int tb = base + CHL + tt;    // == 2047 only at j=127,tt=7

        float dxa[CIN], dxb[CIN];
        loadDx(X, b, ta, dxa);
        loadDx(X, b, tb, dxb);

        // S B-frags
        fx4 sa, sb;
#pragma unroll
        for (int r = 0; r < 4; ++r) {
            float va = 0.f, vb = 0.f;
#pragma unroll
            for (int cc = 0; cc < CIN; ++cc) {
                va = fmaf(dxa[cc], ask[r][cc], va);
                vb = fmaf(dxb[cc], ask[r][cc], vb);
            }
            sa[r] = va; sb[r] = vb;
        }

        // exact inf-norm via MFMA
        const float na = infnormS(sa, Oh);
        const float nb = infnormS(sb, Oh);

        // per-chain exact-pow2 scaling: n*2^-sc < 0.25
        int ea, eb;
        (void)frexpf(na, &ea);
        (void)frexpf(nb, &eb);
        int sca = ea + 2; if (sca < 0) sca = 0;
        int scb = eb + 2; if (scb < 0) scb = 0;
        const float sclA = ldexpf(1.0f, -sca);
        const float sclB = ldexpf(1.0f, -scb);

        fx4 xa = sa * sclA, xb = sb * sclB;
        hx4 XahA, XalA, XahB, XalB;
        {
            fx4 nxa = -xa, nxb = -xb;        // skew: X^T = -X
            splitf(nxa, XahA, XalA);
            splitf(nxb, XahB, XalB);
        }

        // degree-5 Taylor Horner, interleaved
        fx4 Ra, Rb;
#pragma unroll
        for (int r = 0; r < 4; ++r) {
            Ra[r] = fmaf(xa[r], 0.2f, idv[r]);
            Rb[r] = fmaf(xb[r], 0.2f, idv[r]);
        }
#pragma unroll
        for (int k = 4; k >= 1; --k) {
            hx4 RhA, RlA, RhB, RlB;
            splitf(Ra, RhA, RlA);
            splitf(Rb, RhB, RlB);
            fx4 qa = mm3(XahA, XalA, RhA, RlA);
            fx4 qb = mm3(XahB, XalB, RhB, RlB);
            const float inv = 1.f / (float)k;
#pragma unroll
            for (int r = 0; r < 4; ++r) {
                Ra[r] = fmaf(qa[r], inv, idv[r]);
                Rb[r] = fmaf(qb[r], inv, idv[r]);
            }
        }

        // squarings: shared loop bound, per-chain wave-uniform predicates
        const int scm = (sca > scb) ? sca : scb;
        for (int q = 0; q < scm; ++q) {
            if (q < sca) {
                hx4 Rh, Rl, Th, Tl;
                splitf(Ra, Rh, Rl);
                mfmaT(Rh, Rl, Ih, Th, Tl);
                Ra = mm3(Th, Tl, Rh, Rl);
            }
            if (q < scb) {
                hx4 Rh, Rl, Th, Tl;
                splitf(Rb, Rh, Rl);
                mfmaT(Rh, Rl, Ih, Th, Tl);
                Rb = mm3(Th, Tl, Rh, Rl);
            }
        }

        // chains: P0 <- Ra @ P0,  P1 <- Rb @ P1
        P0 = foldQ(Ra, P0, Ih);
        P1 = foldQ(Rb, P1, Ih);
    }

    // merge the two adjacent sub-chains: steps [16j,16j+16) = P1 @ P0
    fx4 P = foldQ(P1, P0, Ih);
    *reinterpret_cast<fx4*>(G + ((size_t)b * NCH + j) * 256 + lane * 4) = P;
}

// reduce (unchanged from r13): 64 blocks x 8 waves; wave w folds chunks
// [16w..16w+16) as two ILP-2 8-chains; LDS combine; wave 0 folds 8 + projects.
__global__ __launch_bounds__(512)
void devnet_reduce(const float* __restrict__ G, const float* __restrict__ W,
                   const float* __restrict__ bias, float* __restrict__ out)
{
    __shared__ __align__(16) float Fs[8][256];
    __shared__ float Zf[256];

    const int tid  = threadIdx.x;
    const int wid  = tid >> 6;     // 0..7
    const int lane = tid & 63;
    const int m    = lane >> 4;
    const int c    = lane & 15;
    const int b    = blockIdx.x;

    fx4 idv;
#pragma unroll
    for (int r = 0; r < 4; ++r) idv[r] = (4 * m + r == c) ? 1.f : 0.f;
    const hx4 Ih = pk4(idv[0], idv[1], idv[2], idv[3]);

    const float* gb    = G + (size_t)b * NCH * 256;
    const float* baseA = gb + (size_t)(wid * 16) * 256;
    const float* baseB = gb + (size_t)(wid * 16 + 8) * 256;

    fx4 AccA = *reinterpret_cast<const fx4*>(baseA + lane * 4);
    fx4 AccB = *reinterpret_cast<const fx4*>(baseB + lane * 4);
#pragma unroll
    for (int k = 1; k < 8; ++k) {
        fx4 Qa = *reinterpret_cast<const fx4*>(baseA + (size_t)k * 256 + lane * 4);
        fx4 Qb = *reinterpret_cast<const fx4*>(baseB + (size_t)k * 256 + lane * 4);
        AccA = foldQ(Qa, AccA, Ih);
        AccB = foldQ(Qb, AccB, Ih);
    }
    fx4 Acc = foldQ(AccB, AccA, Ih);   // later half on the left
    *reinterpret_cast<fx4*>(&Fs[wid][lane * 4]) = Acc;
    __syncthreads();

    if (wid == 0) {
        fx4 Z = *reinterpret_cast<const fx4*>(&Fs[0][lane * 4]);
#pragma unroll
        for (int w = 1; w < 8; ++w) {
            fx4 Q = *reinterpret_cast<const fx4*>(&Fs[w][lane * 4]);
            Z = foldQ(Q, Z, Ih);
        }
#pragma unroll
        for (int r = 0; r < 4; ++r) Zf[(4 * m + r) * 16 + c] = Z[r];

        for (int o = 0; o < 10; ++o) {
            const float* wo = W + o * 256;
            float v = Zf[lane] * wo[lane];
            v = fmaf(Zf[lane + 64],  wo[lane + 64],  v);
            v = fmaf(Zf[lane + 128], wo[lane + 128], v);
            v = fmaf(Zf[lane + 192], wo[lane + 192], v);
#pragma unroll
            for (int off = 32; off >= 1; off >>= 1) v += __shfl_down(v, off, 64);
            if (lane == 0) out[b * 10 + o] = v + bias[o];
        }
    }
}

extern "C" void kernel_launch(void* const* d_in, const int* in_sizes, int n_in,
                              void* d_out, int out_size, void* d_ws, size_t ws_size,
                              hipStream_t stream)
{
    const float* X    = (const float*)d_in[0];
    const float* A    = (const float*)d_in[1];
    const float* W    = (const float*)d_in[2];
    const float* bias = (const float*)d_in[3];
    float* out = (float*)d_out;
    float* G   = (float*)d_ws;   // 64*128*256 floats = 8 MB scratch

    // 8192 waves = BSZ*NCH slots, one slot per wave -> 2048 blocks of 4 waves
    devnet_expm_chunk<<<BSZ * NCH / 4, 256, 0, stream>>>(X, A, G);
    devnet_reduce<<<BSZ, 512, 0, stream>>>(G, W, bias, out);
}

// Round 16
// 172.743 us; speedup vs baseline: 1.1857x; 1.1857x over previous
//
#include <hip/hip_runtime.h>

#define BSZ   64
#define TLEN  2048
#define NSTEP 2047
#define CIN   8
#define NCH   128     // G slots per batch (16 steps each)
#define CHL   8       // steps per sub-chain; wave does two adjacent sub-chains

typedef __attribute__((ext_vector_type(4))) float    fx4;
typedef __attribute__((ext_vector_type(4))) _Float16 hx4;

// pack 4 f32 -> 4 f16 (rtz)
__device__ __forceinline__ hx4 pk4(float a, float b, float c, float d) {
    auto p0 = __builtin_amdgcn_cvt_pkrtz(a, b);
    auto p1 = __builtin_amdgcn_cvt_pkrtz(c, d);
    hx4 r; r[0] = p0[0]; r[1] = p0[1]; r[2] = p1[0]; r[3] = p1[1];
    return r;
}

// f32 -> f16 hi(rne)/lo(rtz) split: hi+lo ~2^-21 relative
__device__ __forceinline__ void splitf(const fx4 v, hx4& hi, hx4& lo) {
    _Float16 h0 = (_Float16)v[0], h1 = (_Float16)v[1];
    _Float16 h2 = (_Float16)v[2], h3 = (_Float16)v[3];
    hi[0] = h0; hi[1] = h1; hi[2] = h2; hi[3] = h3;
    lo = pk4(v[0] - (float)h0, v[1] - (float)h1, v[2] - (float)h2, v[3] - (float)h3);
}

// D = A*B, 3-term split (hh + h*l + l*h)
__device__ __forceinline__ fx4 mm3(hx4 ah, hx4 al, hx4 bh, hx4 bl) {
    fx4 acc = {0.f, 0.f, 0.f, 0.f};
    acc = __builtin_amdgcn_mfma_f32_16x16x16f16(ah, bh, acc, 0, 0, 0);
    acc = __builtin_amdgcn_mfma_f32_16x16x16f16(ah, bl, acc, 0, 0, 0);
    acc = __builtin_amdgcn_mfma_f32_16x16x16f16(al, bh, acc, 0, 0, 0);
    return acc;
}

// exact MFMA transpose of f16 halves
__device__ __forceinline__ void mfmaT(hx4 Mh, hx4 Ml, hx4 Ih, hx4& Th, hx4& Tl) {
    fx4 z = {0.f, 0.f, 0.f, 0.f};
    fx4 th = __builtin_amdgcn_mfma_f32_16x16x16f16(Mh, Ih, z, 0, 0, 0);
    fx4 tl = __builtin_amdgcn_mfma_f32_16x16x16f16(Ml, Ih, z, 0, 0, 0);
    Th = pk4(th[0], th[1], th[2], th[3]);
    Tl = pk4(tl[0], tl[1], tl[2], tl[3]);
}

// Acc <- Q @ Acc
__device__ __forceinline__ fx4 foldQ(fx4 Q, fx4 Acc, hx4 Ih) {
    hx4 Qh, Ql, Th, Tl, Bh, Bl;
    splitf(Q, Qh, Ql);
    mfmaT(Qh, Ql, Ih, Th, Tl);
    splitf(Acc, Bh, Bl);
    return mm3(Th, Tl, Bh, Bl);
}

// inf-norm of skew S via MFMA: rowsum(|S|) broadcast; fmax + 2 shfl
__device__ __forceinline__ float infnormS(fx4 s, hx4 Oh) {
    hx4 sab = pk4(fabsf(s[0]), fabsf(s[1]), fabsf(s[2]), fabsf(s[3]));
    fx4 z = {0.f, 0.f, 0.f, 0.f};
    fx4 rs = __builtin_amdgcn_mfma_f32_16x16x16f16(sab, Oh, z, 0, 0, 0);
    float a = fmaxf(fmaxf(rs[0], rs[1]), fmaxf(rs[2], rs[3]));
    a = fmaxf(a, __shfl_xor(a, 16, 64));
    a = fmaxf(a, __shfl_xor(a, 32, 64));
    return a;
}

__device__ __forceinline__ void loadDx(const float* __restrict__ X, int b, int t,
                                       float dx[CIN]) {
    if (t < NSTEP) {
        const float* xp = X + ((size_t)b * TLEN + t) * CIN;
        const float4 x0 = *reinterpret_cast<const float4*>(xp + 0);
        const float4 x1 = *reinterpret_cast<const float4*>(xp + 4);
        const float4 y0 = *reinterpret_cast<const float4*>(xp + 8);
        const float4 y1 = *reinterpret_cast<const float4*>(xp + 12);
        dx[0] = y0.x - x0.x; dx[1] = y0.y - x0.y; dx[2] = y0.z - x0.z; dx[3] = y0.w - x0.w;
        dx[4] = y1.x - x1.x; dx[5] = y1.y - x1.y; dx[6] = y1.z - x1.z; dx[7] = y1.w - x1.w;
    } else {
#pragma unroll
        for (int i = 0; i < CIN; ++i) dx[i] = 0.f;   // S=0 -> R=I
    }
}

// 8192 waves (2048 blocks x 4 waves): wave j of batch b advances the two
// ADJACENT 8-step sub-chains [16j,16j+8) and [16j+8,16j+16) as ILP-2, merges
// P1@P0, stores one 16-step product to G slot j.
// launch_bounds min-waves=4: VGPR cap 128 -> compiler ~50, NO SPILL; at ~50
// VGPR the HW still allows 8 waves/SIMD residency (512/50 > 8), and the grid
// supplies 8/SIMD. (r15's (256,8) forced 32 VGPR -> 275 MB scratch spill.)
__global__ __launch_bounds__(256, 4)
void devnet_expm_chunk(const float* __restrict__ X, const float* __restrict__ A,
                       float* __restrict__ G)
{
    const int tid  = threadIdx.x;
    const int wid  = tid >> 6;
    const int lane = tid & 63;
    const int m    = lane >> 4;
    const int c    = lane & 15;
    const int gw   = blockIdx.x * 4 + wid;   // 0..8191
    const int b    = gw >> 7;                // 128 waves per batch
    const int j    = gw & 127;               // G slot

    // A_skew fragment: rows 4m+r, col c, 8 channels
    float ask[4][CIN];
#pragma unroll
    for (int r = 0; r < 4; ++r) {
        const int i = 4 * m + r;
#pragma unroll
        for (int cc = 0; cc < CIN; ++cc)
            ask[r][cc] = A[(i * 16 + c) * CIN + cc] - A[(c * 16 + i) * CIN + cc];
    }

    fx4 idv;
#pragma unroll
    for (int r = 0; r < 4; ++r) idv[r] = (4 * m + r == c) ? 1.f : 0.f;
    const hx4 Ih = pk4(idv[0], idv[1], idv[2], idv[3]);
    const hx4 Oh = pk4(1.f, 1.f, 1.f, 1.f);

    fx4 P0 = idv, P1 = idv;
    const int base = 16 * j;

    for (int tt = 0; tt < CHL; ++tt) {
        const int ta = base + tt;          // <= 2039: always valid
        const int tb = base + CHL + tt;    // == 2047 only at j=127,tt=7

        float dxa[CIN], dxb[CIN];
        loadDx(X, b, ta, dxa);
        loadDx(X, b, tb, dxb);

        // S B-frags
        fx4 sa, sb;
#pragma unroll
        for (int r = 0; r < 4; ++r) {
            float va = 0.f, vb = 0.f;
#pragma unroll
            for (int cc = 0; cc < CIN; ++cc) {
                va = fmaf(dxa[cc], ask[r][cc], va);
                vb = fmaf(dxb[cc], ask[r][cc], vb);
            }
            sa[r] = va; sb[r] = vb;
        }

        // exact inf-norm via MFMA
        const float na = infnormS(sa, Oh);
        const float nb = infnormS(sb, Oh);

        // per-chain exact-pow2 scaling: n*2^-sc < 0.25
        int ea, eb;
        (void)frexpf(na, &ea);
        (void)frexpf(nb, &eb);
        int sca = ea + 2; if (sca < 0) sca = 0;
        int scb = eb + 2; if (scb < 0) scb = 0;
        const float sclA = ldexpf(1.0f, -sca);
        const float sclB = ldexpf(1.0f, -scb);

        fx4 xa = sa * sclA, xb = sb * sclB;
        hx4 XahA, XalA, XahB, XalB;
        {
            fx4 nxa = -xa, nxb = -xb;        // skew: X^T = -X
            splitf(nxa, XahA, XalA);
            splitf(nxb, XahB, XalB);
        }

        // degree-5 Taylor Horner, interleaved
        fx4 Ra, Rb;
#pragma unroll
        for (int r = 0; r < 4; ++r) {
            Ra[r] = fmaf(xa[r], 0.2f, idv[r]);
            Rb[r] = fmaf(xb[r], 0.2f, idv[r]);
        }
#pragma unroll
        for (int k = 4; k >= 1; --k) {
            hx4 RhA, RlA, RhB, RlB;
            splitf(Ra, RhA, RlA);
            splitf(Rb, RhB, RlB);
            fx4 qa = mm3(XahA, XalA, RhA, RlA);
            fx4 qb = mm3(XahB, XalB, RhB, RlB);
            const float inv = 1.f / (float)k;
#pragma unroll
            for (int r = 0; r < 4; ++r) {
                Ra[r] = fmaf(qa[r], inv, idv[r]);
                Rb[r] = fmaf(qb[r], inv, idv[r]);
            }
        }

        // squarings: shared loop bound, per-chain wave-uniform predicates
        const int scm = (sca > scb) ? sca : scb;
        for (int q = 0; q < scm; ++q) {
            if (q < sca) {
                hx4 Rh, Rl, Th, Tl;
                splitf(Ra, Rh, Rl);
                mfmaT(Rh, Rl, Ih, Th, Tl);
                Ra = mm3(Th, Tl, Rh, Rl);
            }
            if (q < scb) {
                hx4 Rh, Rl, Th, Tl;
                splitf(Rb, Rh, Rl);
                mfmaT(Rh, Rl, Ih, Th, Tl);
                Rb = mm3(Th, Tl, Rh, Rl);
            }
        }

        // chains: P0 <- Ra @ P0,  P1 <- Rb @ P1
        P0 = foldQ(Ra, P0, Ih);
        P1 = foldQ(Rb, P1, Ih);
    }

    // merge the two adjacent sub-chains: steps [16j,16j+16) = P1 @ P0
    fx4 P = foldQ(P1, P0, Ih);
    *reinterpret_cast<fx4*>(G + ((size_t)b * NCH + j) * 256 + lane * 4) = P;
}

// reduce (unchanged): 64 blocks x 8 waves; wave w folds chunks [16w..16w+16)
// as two ILP-2 8-chains; LDS combine; wave 0 folds 8 + projects.
__global__ __launch_bounds__(512)
void devnet_reduce(const float* __restrict__ G, const float* __restrict__ W,
                   const float* __restrict__ bias, float* __restrict__ out)
{
    __shared__ __align__(16) float Fs[8][256];
    __shared__ float Zf[256];

    const int tid  = threadIdx.x;
    const int wid  = tid >> 6;     // 0..7
    const int lane = tid & 63;
    const int m    = lane >> 4;
    const int c    = lane & 15;
    const int b    = blockIdx.x;

    fx4 idv;
#pragma unroll
    for (int r = 0; r < 4; ++r) idv[r] = (4 * m + r == c) ? 1.f : 0.f;
    const hx4 Ih = pk4(idv[0], idv[1], idv[2], idv[3]);

    const float* gb    = G + (size_t)b * NCH * 256;
    const float* baseA = gb + (size_t)(wid * 16) * 256;
    const float* baseB = gb + (size_t)(wid * 16 + 8) * 256;

    fx4 AccA = *reinterpret_cast<const fx4*>(baseA + lane * 4);
    fx4 AccB = *reinterpret_cast<const fx4*>(baseB + lane * 4);
#pragma unroll
    for (int k = 1; k < 8; ++k) {
        fx4 Qa = *reinterpret_cast<const fx4*>(baseA + (size_t)k * 256 + lane * 4);
        fx4 Qb = *reinterpret_cast<const fx4*>(baseB + (size_t)k * 256 + lane * 4);
        AccA = foldQ(Qa, AccA, Ih);
        AccB = foldQ(Qb, AccB, Ih);
    }
    fx4 Acc = foldQ(AccB, AccA, Ih);   // later half on the left
    *reinterpret_cast<fx4*>(&Fs[wid][lane * 4]) = Acc;
    __syncthreads();

    if (wid == 0) {
        fx4 Z = *reinterpret_cast<const fx4*>(&Fs[0][lane * 4]);
#pragma unroll
        for (int w = 1; w < 8; ++w) {
            fx4 Q = *reinterpret_cast<const fx4*>(&Fs[w][lane * 4]);
            Z = foldQ(Q, Z, Ih);
        }
#pragma unroll
        for (int r = 0; r < 4; ++r) Zf[(4 * m + r) * 16 + c] = Z[r];

        for (int o = 0; o < 10; ++o) {
            const float* wo = W + o * 256;
            float v = Zf[lane] * wo[lane];
            v = fmaf(Zf[lane + 64],  wo[lane + 64],  v);
            v = fmaf(Zf[lane + 128], wo[lane + 128], v);
            v = fmaf(Zf[lane + 192], wo[lane + 192], v);
#pragma unroll
            for (int off = 32; off >= 1; off >>= 1) v += __shfl_down(v, off, 64);
            if (lane == 0) out[b * 10 + o] = v + bias[o];
        }
    }
}

extern "C" void kernel_launch(void* const* d_in, const int* in_sizes, int n_in,
                              void* d_out, int out_size, void* d_ws, size_t ws_size,
                              hipStream_t stream)
{
    const float* X    = (const float*)d_in[0];
    const float* A    = (const float*)d_in[1];
    const float* W    = (const float*)d_in[2];
    const float* bias = (const float*)d_in[3];
    float* out = (float*)d_out;
    float* G   = (float*)d_ws;   // 64*128*256 floats = 8 MB scratch

    // 8192 waves = BSZ*NCH slots, one slot per wave -> 2048 blocks of 4 waves
    devnet_expm_chunk<<<BSZ * NCH / 4, 256, 0, stream>>>(X, A, G);
    devnet_reduce<<<BSZ, 512, 0, stream>>>(G, W, bias, out);
}